// Round 1
// baseline (592.955 us; speedup 1.0000x reference)
//
#include <hip/hip_runtime.h>
#include <math.h>

namespace {
constexpr int B_   = 8;
constexpr int NIN  = 32;
constexpr int H_   = 14;
constexpr int CIN  = 8;
constexpr int C_   = 32;
constexpr int COUT = 16;
constexpr int K_   = 3;
constexpr int R_   = NIN * K_ * K_;   // 288
constexpr int W_   = 12;              // output spatial
constexpr int NITER = 3;
}

// One block per (c, b, p, q). Priors tile (288 x 16) lives in LDS; the whole
// routing loop runs in-block (probs are o-independent, see analysis).
__global__ __launch_bounds__(256)
void caps_route_kernel(const float* __restrict__ x,
                       const float* __restrict__ rw,
                       float* __restrict__ out)
{
    const int tid = threadIdx.x;
    const int p = blockIdx.x / W_;
    const int q = blockIdx.x % W_;
    const int b = blockIdx.y;
    const int c = blockIdx.z;

    __shared__ float winS[R_ * CIN];      // 2304 floats
    __shared__ float pri[R_ * COUT];      // 4608 floats
    __shared__ float logitsS[R_];
    __shared__ float probsS[R_];
    __shared__ float sS[COUT];
    __shared__ float vS[COUT];
    __shared__ float redS[64];
    __shared__ float scalS;

    // ---- stage window: winS[r][i] = x[b, n, p+kh, q+kw, i], r = n*9+kh*3+kw
    for (int idx = tid; idx < R_ * CIN; idx += 256) {
        int i  = idx & (CIN - 1);
        int r  = idx >> 3;
        int kw = r % K_;
        int kh = (r / K_) % K_;
        int n  = r / (K_ * K_);
        winS[idx] = x[(((b * NIN + n) * H_ + (p + kh)) * H_ + (q + kw)) * CIN + i];
    }
    for (int r = tid; r < R_; r += 256) logitsS[r] = 0.0f;
    __syncthreads();

    // ---- priors: pri[r][o] = sum_i winS[r][i] * rw[c][r][i][o]
    const int o  = tid & 15;    // 0..15
    const int rl = tid >> 4;    // 0..15
    for (int j = 0; j < R_ / 16; ++j) {
        int r = j * 16 + rl;
        const float* wp = rw + ((size_t)(c * R_ + r) * CIN) * COUT + o;
        float acc = 0.0f;
        #pragma unroll
        for (int i = 0; i < CIN; ++i)
            acc = fmaf(winS[r * CIN + i], wp[i * COUT], acc);
        pri[r * COUT + o] = acc;
    }
    __syncthreads();

    const int wv   = tid >> 6;  // wave id 0..3
    const int lane = tid & 63;

    for (int it = 0; it < NITER; ++it) {
        if (it == 0) {
            const float u = 1.0f / (float)R_;
            for (int r = tid; r < R_; r += 256) probsS[r] = u;
            __syncthreads();
        } else {
            // softmax over logitsS[0..R_)
            float m = -3.0e38f;
            for (int r = tid; r < R_; r += 256) m = fmaxf(m, logitsS[r]);
            #pragma unroll
            for (int off = 32; off >= 1; off >>= 1) m = fmaxf(m, __shfl_xor(m, off, 64));
            if (lane == 0) redS[wv] = m;
            __syncthreads();
            if (tid == 0) scalS = fmaxf(fmaxf(redS[0], redS[1]), fmaxf(redS[2], redS[3]));
            __syncthreads();
            const float mm = scalS;
            float se = 0.0f;
            for (int r = tid; r < R_; r += 256) {
                float e = expf(logitsS[r] - mm);
                probsS[r] = e;
                se += e;
            }
            #pragma unroll
            for (int off = 32; off >= 1; off >>= 1) se += __shfl_xor(se, off, 64);
            if (lane == 0) redS[wv] = se;
            __syncthreads();
            if (tid == 0) scalS = redS[0] + redS[1] + redS[2] + redS[3];
            __syncthreads();
            const float inv = 1.0f / scalS;
            for (int r = tid; r < R_; r += 256) probsS[r] *= inv;
            __syncthreads();
        }

        // s[o] = sum_r probs[r] * pri[r][o]
        float part = 0.0f;
        for (int j = 0; j < R_ / 16; ++j) {
            int r = j * 16 + rl;
            part = fmaf(probsS[r], pri[r * COUT + o], part);
        }
        // reduce over rl: within wave (rl bits are lane bits 4..5), then across 4 waves
        part += __shfl_xor(part, 16, 64);
        part += __shfl_xor(part, 32, 64);
        if (lane < 16) redS[wv * 16 + lane] = part;  // lane<16 => o == lane
        __syncthreads();
        if (tid < COUT)
            sS[tid] = redS[tid] + redS[16 + tid] + redS[32 + tid] + redS[48 + tid];
        __syncthreads();
        if (tid == 0) {
            float sn = 0.0f;
            #pragma unroll
            for (int oo = 0; oo < COUT; ++oo) sn += sS[oo] * sS[oo];
            // squash coefficient: sn/(1+sn) / sqrt(sn) = sqrt(sn)/(1+sn)
            scalS = sqrtf(sn) / (1.0f + sn);
        }
        __syncthreads();
        if (tid < COUT) vS[tid] = sS[tid] * scalS;
        __syncthreads();

        if (it != NITER - 1) {
            // logits[r] += sum_o pri[r][o] * v[o]
            for (int j = 0; j < R_ / 16; ++j) {
                int r = j * 16 + rl;
                float t = pri[r * COUT + o] * vS[o];
                t += __shfl_xor(t, 1, 64);
                t += __shfl_xor(t, 2, 64);
                t += __shfl_xor(t, 4, 64);
                t += __shfl_xor(t, 8, 64);
                if (o == 0) logitsS[r] += t;
            }
            __syncthreads();
        }
    }

    // out[b][c][p][q][o]
    if (tid < COUT)
        out[((((size_t)b * C_ + c) * W_ + p) * W_ + q) * COUT + tid] = vS[tid];
}

extern "C" void kernel_launch(void* const* d_in, const int* in_sizes, int n_in,
                              void* d_out, int out_size, void* d_ws, size_t ws_size,
                              hipStream_t stream) {
    const float* x  = (const float*)d_in[0];
    const float* rw = (const float*)d_in[1];
    float* out = (float*)d_out;
    dim3 grid(W_ * W_, B_, C_);
    caps_route_kernel<<<grid, 256, 0, stream>>>(x, rw, out);
}

// Round 3
// 361.447 us; speedup vs baseline: 1.6405x; 1.6405x over previous
//
#include <hip/hip_runtime.h>
#include <math.h>

namespace {
constexpr int B_    = 8;
constexpr int NIN   = 32;
constexpr int H_    = 14;
constexpr int CIN   = 8;
constexpr int C_    = 32;
constexpr int COUT  = 16;
constexpr int R_    = 288;
constexpr int W_    = 12;
constexpr int NITER = 3;
constexpr size_t XSUB = (size_t)NIN * H_ * H_ * CIN;   // x stride per batch elem
}

__device__ __forceinline__ float dot4(const float4 a, const float4 b) {
    return fmaf(a.x, b.x, fmaf(a.y, b.y, fmaf(a.z, b.z, a.w * b.w)));
}

// Compute one prior row pair: a0/a1 = priors for (r, outputs og*4..og*4+3),
// batch elems b0 and b0+1. W float4 read once, used for both subs.
__device__ __forceinline__ void prior_one(const float* __restrict__ x0,
                                          const float* __restrict__ rwc,
                                          int r, int p, int q, int og,
                                          float4& a0, float4& a1)
{
    const int n   = r / 9;
    const int rem = r - n * 9;
    const int kh  = rem / 3;
    const int kw  = rem - kh * 3;
    const float* xp = x0 + ((n * H_ + (p + kh)) * H_ + (q + kw)) * CIN;
    const float4 xa = *(const float4*)xp;
    const float4 xb = *(const float4*)(xp + 4);
    const float4 ya = *(const float4*)(xp + XSUB);
    const float4 yb = *(const float4*)(xp + XSUB + 4);
    const float xs0[8] = {xa.x, xa.y, xa.z, xa.w, xb.x, xb.y, xb.z, xb.w};
    const float xs1[8] = {ya.x, ya.y, ya.z, ya.w, yb.x, yb.y, yb.z, yb.w};
    const float4* wp = (const float4*)(rwc + (size_t)r * CIN * COUT) + og;
    float4 r0 = make_float4(0.f, 0.f, 0.f, 0.f);
    float4 r1 = make_float4(0.f, 0.f, 0.f, 0.f);
    #pragma unroll
    for (int i = 0; i < CIN; ++i) {
        const float4 wv = wp[i * 4];
        r0.x = fmaf(xs0[i], wv.x, r0.x);  r1.x = fmaf(xs1[i], wv.x, r1.x);
        r0.y = fmaf(xs0[i], wv.y, r0.y);  r1.y = fmaf(xs1[i], wv.y, r1.y);
        r0.z = fmaf(xs0[i], wv.z, r0.z);  r1.z = fmaf(xs1[i], wv.z, r1.z);
        r0.w = fmaf(xs0[i], wv.w, r0.w);  r1.w = fmaf(xs1[i], wv.w, r1.w);
    }
    a0 = r0; a1 = r1;
}

// One block per (c, b-pair, p, q). Priors (288 x 16 x 2 subs) live in
// REGISTERS spread over the block: thread (og, rl) owns r = rl + 64j
// (j=0..3; +r=256+rl for rl<32 — wave-uniform) x outputs og*4..og*4+3.
__global__ __launch_bounds__(256)
void caps_route3(const float* __restrict__ x,
                 const float* __restrict__ rw,
                 float* __restrict__ out)
{
    const int tid = threadIdx.x;
    const int p  = blockIdx.x / W_;
    const int q  = blockIdx.x % W_;
    const int b0 = blockIdx.y * 2;
    const int c  = blockIdx.z;

    __shared__ float logitsS[2][R_];
    __shared__ float probsS[2][R_];
    __shared__ float sRed[4][2][16];
    __shared__ float redM[2][2];
    __shared__ float redE[2][2];
    __shared__ float vS[2][16];

    const int og   = tid & 3;
    const int rl   = tid >> 2;
    const int lane = tid & 63;
    const int wv   = tid >> 6;
    const bool hasJ4 = (rl < 32);       // true for waves 0,1 — wave-uniform

    for (int t = tid; t < 2 * R_; t += 256) {
        (&logitsS[0][0])[t] = 0.0f;
        (&probsS[0][0])[t]  = 1.0f;     // iter-0 probs, scaled by 1/R in s-phase
    }

    // ---- priors in registers
    const float* x0  = x + (size_t)b0 * XSUB;
    const float* rwc = rw + (size_t)c * R_ * CIN * COUT;
    float4 acc[5][2];
    #pragma unroll
    for (int j = 0; j < 4; ++j)
        prior_one(x0, rwc, rl + 64 * j, p, q, og, acc[j][0], acc[j][1]);
    if (hasJ4)
        prior_one(x0, rwc, 256 + rl, p, q, og, acc[4][0], acc[4][1]);
    __syncthreads();   // covers logits/probs init

    for (int it = 0; it < NITER; ++it) {
        float inv0, inv1;
        if (it == 0) {
            inv0 = inv1 = 1.0f / (float)R_;
        } else {
            // softmax over logits, per sub: threads 0..127 -> sub0, rest sub1
            const int t    = tid & 127;
            const int subR = tid >> 7;
            const int wv2  = (tid >> 6) & 1;
            float m = fmaxf(logitsS[subR][t], logitsS[subR][t + 128]);
            if (t < 32) m = fmaxf(m, logitsS[subR][t + 256]);
            #pragma unroll
            for (int off = 32; off >= 1; off >>= 1)
                m = fmaxf(m, __shfl_xor(m, off, 64));
            if (lane == 0) redM[subR][wv2] = m;
            __syncthreads();
            const float mm = fmaxf(redM[subR][0], redM[subR][1]);
            float se = 0.0f;
            {
                float e0 = expf(logitsS[subR][t] - mm);
                float e1 = expf(logitsS[subR][t + 128] - mm);
                probsS[subR][t]       = e0;
                probsS[subR][t + 128] = e1;
                se = e0 + e1;
                if (t < 32) {
                    float e2 = expf(logitsS[subR][t + 256] - mm);
                    probsS[subR][t + 256] = e2;
                    se += e2;
                }
            }
            #pragma unroll
            for (int off = 32; off >= 1; off >>= 1)
                se += __shfl_xor(se, off, 64);
            if (lane == 0) redE[subR][wv2] = se;
            __syncthreads();
            inv0 = 1.0f / (redE[0][0] + redE[0][1]);
            inv1 = 1.0f / (redE[1][0] + redE[1][1]);
        }

        // ---- s[o] = inv * sum_r probs[r] * pri[r][o]   (priors in regs)
        float4 s0 = make_float4(0.f, 0.f, 0.f, 0.f);
        float4 s1 = make_float4(0.f, 0.f, 0.f, 0.f);
        #pragma unroll
        for (int j = 0; j < 4; ++j) {
            const int r = rl + 64 * j;
            const float p0 = probsS[0][r], p1 = probsS[1][r];
            s0.x = fmaf(p0, acc[j][0].x, s0.x);  s1.x = fmaf(p1, acc[j][1].x, s1.x);
            s0.y = fmaf(p0, acc[j][0].y, s0.y);  s1.y = fmaf(p1, acc[j][1].y, s1.y);
            s0.z = fmaf(p0, acc[j][0].z, s0.z);  s1.z = fmaf(p1, acc[j][1].z, s1.z);
            s0.w = fmaf(p0, acc[j][0].w, s0.w);  s1.w = fmaf(p1, acc[j][1].w, s1.w);
        }
        if (hasJ4) {
            const int r = 256 + rl;
            const float p0 = probsS[0][r], p1 = probsS[1][r];
            s0.x = fmaf(p0, acc[4][0].x, s0.x);  s1.x = fmaf(p1, acc[4][1].x, s1.x);
            s0.y = fmaf(p0, acc[4][0].y, s0.y);  s1.y = fmaf(p1, acc[4][1].y, s1.y);
            s0.z = fmaf(p0, acc[4][0].z, s0.z);  s1.z = fmaf(p1, acc[4][1].z, s1.z);
            s0.w = fmaf(p0, acc[4][0].w, s0.w);  s1.w = fmaf(p1, acc[4][1].w, s1.w);
        }
        s0.x *= inv0; s0.y *= inv0; s0.z *= inv0; s0.w *= inv0;
        s1.x *= inv1; s1.y *= inv1; s1.z *= inv1; s1.w *= inv1;
        // reduce over rl within wave (rl bits = lane bits 2..5)
        #pragma unroll
        for (int off = 4; off <= 32; off <<= 1) {
            s0.x += __shfl_xor(s0.x, off, 64);  s1.x += __shfl_xor(s1.x, off, 64);
            s0.y += __shfl_xor(s0.y, off, 64);  s1.y += __shfl_xor(s1.y, off, 64);
            s0.z += __shfl_xor(s0.z, off, 64);  s1.z += __shfl_xor(s1.z, off, 64);
            s0.w += __shfl_xor(s0.w, off, 64);  s1.w += __shfl_xor(s1.w, off, 64);
        }
        if (lane < 4) {   // lane == og here
            *(float4*)&sRed[wv][0][lane * 4] = s0;
            *(float4*)&sRed[wv][1][lane * 4] = s1;
        }
        __syncthreads();

        // ---- squash (32 threads: sb, o)
        if (tid < 32) {
            const int sb = tid >> 4;
            const int o  = tid & 15;
            float s = sRed[0][sb][o] + sRed[1][sb][o]
                    + sRed[2][sb][o] + sRed[3][sb][o];
            float sn = s * s;
            #pragma unroll
            for (int off = 1; off <= 8; off <<= 1) sn += __shfl_xor(sn, off, 64);
            const float v = s * (sqrtf(sn) / (1.0f + sn));
            if (it == NITER - 1) {
                out[((((size_t)(b0 + sb) * C_ + c) * W_ + p) * W_ + q) * COUT + o] = v;
            } else {
                vS[sb][o] = v;
            }
        }
        if (it == NITER - 1) break;
        __syncthreads();

        // ---- logits[r] += sum_o pri[r][o] * v[o]
        const float4 v0 = *(const float4*)&vS[0][og * 4];
        const float4 v1 = *(const float4*)&vS[1][og * 4];
        #pragma unroll
        for (int j = 0; j < 4; ++j) {
            const int r = rl + 64 * j;
            float d0 = dot4(acc[j][0], v0);
            float d1 = dot4(acc[j][1], v1);
            d0 += __shfl_xor(d0, 1, 64);  d1 += __shfl_xor(d1, 1, 64);
            d0 += __shfl_xor(d0, 2, 64);  d1 += __shfl_xor(d1, 2, 64);
            if (og == 0) { logitsS[0][r] += d0; logitsS[1][r] += d1; }
        }
        if (hasJ4) {
            const int r = 256 + rl;
            float d0 = dot4(acc[4][0], v0);
            float d1 = dot4(acc[4][1], v1);
            d0 += __shfl_xor(d0, 1, 64);  d1 += __shfl_xor(d1, 1, 64);
            d0 += __shfl_xor(d0, 2, 64);  d1 += __shfl_xor(d1, 2, 64);
            if (og == 0) { logitsS[0][r] += d0; logitsS[1][r] += d1; }
        }
        __syncthreads();
    }
}

extern "C" void kernel_launch(void* const* d_in, const int* in_sizes, int n_in,
                              void* d_out, int out_size, void* d_ws, size_t ws_size,
                              hipStream_t stream) {
    const float* x  = (const float*)d_in[0];
    const float* rw = (const float*)d_in[1];
    float* out = (float*)d_out;
    dim3 grid(W_ * W_, B_ / 2, C_);
    caps_route3<<<grid, 256, 0, stream>>>(x, rw, out);
}